// Round 6
// baseline (424.365 us; speedup 1.0000x reference)
//
#include <hip/hip_runtime.h>
#include <hip/hip_fp16.h>
#include <math.h>

#define IN_CH 16
#define HC1 128   // H1*C1
#define NH1 4
#define C2 32
#define HID 64
#define NEG 0.2f
#define SCAN_B 256
#define NPART 8

typedef float f4v __attribute__((ext_vector_type(4)));

__device__ __forceinline__ int ntl_i(const int* p) { return __builtin_nontemporal_load(p); }
__device__ __forceinline__ float ntl_f(const float* p) { return __builtin_nontemporal_load(p); }
__device__ __forceinline__ float4 ntl_f4(const float4* p) {
    f4v v = __builtin_nontemporal_load((const f4v*)p);
    return *(float4*)&v;
}
__device__ __forceinline__ void nts_f4(float4* p, float4 v) {
    __builtin_nontemporal_store(*(f4v*)&v, (f4v*)p);
}
__device__ __forceinline__ void nts_u(unsigned* p, unsigned v) {
    __builtin_nontemporal_store(v, p);
}

__device__ __forceinline__ float lrelu_exp(float z) {
    float lr = z > 0.f ? z : NEG * z;
    return expf(lr);
}

// ---- CSR build ----
// XCD-partitioned degree count; ei reads are NT so the streaming pass does
// not evict the partition's hot deg[] lines from its L2.
__global__ void k_deg(const int* __restrict__ ei, int E, int N, int npp,
                      int* __restrict__ deg) {
    int part = blockIdx.x & (NPART - 1);
    int wg = blockIdx.x >> 3;
    int nwg = gridDim.x >> 3;
    int lo_n = part * npp;
    int hi_n = lo_n + npp;
    int M = E + N;
    for (int i = wg * blockDim.x + threadIdx.x; i < M; i += nwg * blockDim.x) {
        int dst = (i < E) ? ntl_i(ei + E + i) : (i - E);
        if (dst >= lo_n && dst < hi_n) atomicAdd(&deg[dst], 1);
    }
}

__global__ void k_scan1(const int* __restrict__ deg, int N, int* __restrict__ tmp, int* __restrict__ bsum) {
    __shared__ int s[SCAN_B];
    int i = blockIdx.x * SCAN_B + threadIdx.x;
    int v = (i < N) ? deg[i] : 0;
    s[threadIdx.x] = v;
    __syncthreads();
    for (int o = 1; o < SCAN_B; o <<= 1) {
        int add = (threadIdx.x >= o) ? s[threadIdx.x - o] : 0;
        __syncthreads();
        s[threadIdx.x] += add;
        __syncthreads();
    }
    if (i < N) tmp[i] = s[threadIdx.x];
    if (threadIdx.x == SCAN_B - 1) bsum[blockIdx.x] = s[SCAN_B - 1];
}

__global__ void k_scan2(const int* __restrict__ bsum, int nb, int* __restrict__ boff,
                        int* __restrict__ offsets, int N) {
    __shared__ int s[1024];
    int t = threadIdx.x;
    int v = (t < nb) ? bsum[t] : 0;
    s[t] = v;
    __syncthreads();
    for (int o = 1; o < 1024; o <<= 1) {
        int add = (t >= o) ? s[t - o] : 0;
        __syncthreads();
        s[t] += add;
        __syncthreads();
    }
    if (t < nb) boff[t] = s[t] - v;
    if (t == nb - 1) offsets[N] = s[t];
}

__global__ void k_scan3(const int* __restrict__ deg, const int* __restrict__ tmp,
                        const int* __restrict__ boff, int N,
                        int* __restrict__ offsets, int* __restrict__ cursor) {
    int i = blockIdx.x * SCAN_B + threadIdx.x;
    if (i >= N) return;
    int excl = tmp[i] - deg[i] + boff[blockIdx.x];
    offsets[i] = excl;
    cursor[i] = excl;
}

// XCD-partitioned scatter; NT reads of ei keep dirty elist lines resident
// in the partition's L2 so partial lines merge before writeback.
__global__ void k_scatter(const int* __restrict__ ei, int E, int N, int npp,
                          int* __restrict__ cursor, int* __restrict__ elist) {
    int part = blockIdx.x & (NPART - 1);
    int wg = blockIdx.x >> 3;
    int nwg = gridDim.x >> 3;
    int lo_n = part * npp;
    int hi_n = lo_n + npp;
    int M = E + N;
    for (int i = wg * blockDim.x + threadIdx.x; i < M; i += nwg * blockDim.x) {
        int dst = (i < E) ? ntl_i(ei + E + i) : (i - E);
        if (dst >= lo_n && dst < hi_n) {
            int src = (i < E) ? ntl_i(ei + i) : dst;
            int pos = atomicAdd(&cursor[dst], 1);
            elist[pos] = src;
        }
    }
}

// ---- GAT1 linear + logits: one wave per node, 2 channels/lane ----
__global__ void k_lin1(const float* __restrict__ x, const float2* __restrict__ W1v,
                       const float2* __restrict__ att_s2, const float2* __restrict__ att_d2,
                       int N, __half2* __restrict__ h1h, float* __restrict__ as1, float* __restrict__ ad1) {
    int wave = threadIdx.x >> 6;
    int lane = threadIdx.x & 63;
    int n = blockIdx.x * 4 + wave;
    if (n >= N) return;
    float xv = ntl_f(x + n * IN_CH + (lane & 15));
    float ax = 0.f, ay = 0.f;
#pragma unroll
    for (int k = 0; k < IN_CH; ++k) {
        float xk = __shfl(xv, k, 16);
        float2 w = W1v[k * 64 + lane];
        ax += xk * w.x;
        ay += xk * w.y;
    }
    __half2 hp = __floats2half2_rn(ax, ay);
    nts_u((unsigned*)(h1h + (size_t)n * 64 + lane), *(unsigned*)&hp);
    float2 s2 = att_s2[lane], d2 = att_d2[lane];
    float vs = ax * s2.x + ay * s2.y;
    float vd = ax * d2.x + ay * d2.y;
#pragma unroll
    for (int o = 1; o < 16; o <<= 1) {
        vs += __shfl_xor(vs, o, 64);
        vd += __shfl_xor(vd, o, 64);
    }
    if ((lane & 15) == 0) {
        as1[n * NH1 + (lane >> 4)] = vs;
        ad1[n * NH1 + (lane >> 4)] = vd;
    }
}

// ---- GAT1 aggregation: one wave per dst; 4 edge-slots x 16 lanes x float4,
//      16 edges in flight; elist NT, out1 NT-store, h1 gathers keep L2 ----
__global__ void k_agg1(const int* __restrict__ offsets, const int* __restrict__ elist,
                       const float* __restrict__ as1, const float* __restrict__ ad1,
                       const float4* __restrict__ h1q, const float* __restrict__ b1,
                       int N, float4* __restrict__ out1q) {
    int wave = threadIdx.x >> 6;
    int lane = threadIdx.x & 63;
    int n = blockIdx.x * 4 + wave;
    if (n >= N) return;
    int slot = lane >> 4, chunk = lane & 15, head = chunk >> 2;
    int lo = offsets[n], hi = offsets[n + 1];
    float adh = ad1[n * NH1 + head];
    float acc[8];
#pragma unroll
    for (int j = 0; j < 8; ++j) acc[j] = 0.f;
    float sumw = 0.f;
#pragma unroll 2
    for (int e0 = lo; e0 < hi; e0 += 8) {
        int eA = e0 + slot, eB = e0 + 4 + slot;
        bool okA = eA < hi, okB = eB < hi;
        int sA = ntl_i(elist + (okA ? eA : lo));
        int sB = ntl_i(elist + (okB ? eB : lo));
        float zA = as1[sA * NH1 + head];
        float zB = as1[sB * NH1 + head];
        float4 vA = h1q[(size_t)sA * 16 + chunk];
        float4 vB = h1q[(size_t)sB * 16 + chunk];
        float wA = okA ? lrelu_exp(zA + adh) : 0.f;
        float wB = okB ? lrelu_exp(zB + adh) : 0.f;
        const __half2* hA = (const __half2*)&vA;
        const __half2* hB = (const __half2*)&vB;
#pragma unroll
        for (int j = 0; j < 4; ++j) {
            float2 fA = __half22float2(hA[j]);
            float2 fB = __half22float2(hB[j]);
            acc[2 * j]     += wA * fA.x + wB * fB.x;
            acc[2 * j + 1] += wA * fA.y + wB * fB.y;
        }
        sumw += wA + wB;
    }
#pragma unroll
    for (int j = 0; j < 8; ++j) {
        acc[j] += __shfl_xor(acc[j], 16, 64);
        acc[j] += __shfl_xor(acc[j], 32, 64);
    }
    sumw += __shfl_xor(sumw, 16, 64);
    sumw += __shfl_xor(sumw, 32, 64);
    if (slot == 0) {
        float inv = 1.f / (sumw + 1e-16f);
        float4 ba = ((const float4*)b1)[2 * chunk];
        float4 bb = ((const float4*)b1)[2 * chunk + 1];
        float o[8];
        o[0] = acc[0] * inv + ba.x; o[1] = acc[1] * inv + ba.y;
        o[2] = acc[2] * inv + ba.z; o[3] = acc[3] * inv + ba.w;
        o[4] = acc[4] * inv + bb.x; o[5] = acc[5] * inv + bb.y;
        o[6] = acc[6] * inv + bb.z; o[7] = acc[7] * inv + bb.w;
#pragma unroll
        for (int j = 0; j < 8; ++j) o[j] = o[j] > 0.f ? o[j] : expm1f(o[j]);
        float4 pk;
        __half2* ph = (__half2*)&pk;
        ph[0] = __floats2half2_rn(o[0], o[1]);
        ph[1] = __floats2half2_rn(o[2], o[3]);
        ph[2] = __floats2half2_rn(o[4], o[5]);
        ph[3] = __floats2half2_rn(o[6], o[7]);
        nts_f4(out1q + (size_t)n * 16 + chunk, pk);
    }
}

// ---- GAT2 linear: LDS-tiled GEMM [N,128](fp16) x [128,32] + logits ----
#define TN 64
__global__ void k_lin2(const __half2* __restrict__ out1h, const float* __restrict__ W2,
                       const float* __restrict__ att_s, const float* __restrict__ att_d,
                       int N, __half2* __restrict__ h2h, float* __restrict__ as2, float* __restrict__ ad2) {
    __shared__ float sx[TN][HC1 + 1];
    __shared__ float sw[HC1][C2];
    int t = threadIdx.x;  // 256
    int base = blockIdx.x * TN;
    int lim = (N - base) * HC1;
    for (int i = t * 4; i < HC1 * C2; i += 1024) {
        float4 v = *(const float4*)(W2 + i);
        sw[i >> 5][i & 31] = v.x;
        sw[i >> 5][(i & 31) + 1] = v.y;
        sw[i >> 5][(i & 31) + 2] = v.z;
        sw[i >> 5][(i & 31) + 3] = v.w;
    }
    for (int i = t * 4; i < TN * HC1; i += 1024) {
        float2 a = make_float2(0.f, 0.f), b = make_float2(0.f, 0.f);
        if (i < lim) {
            const unsigned* ps = (const unsigned*)(out1h + (((size_t)base * HC1 + i) >> 1));
            unsigned ua = __builtin_nontemporal_load(ps);
            unsigned ub = __builtin_nontemporal_load(ps + 1);
            a = __half22float2(*(const __half2*)&ua);
            b = __half22float2(*(const __half2*)&ub);
        }
        int nn = i >> 7, kk = i & 127;
        sx[nn][kk] = a.x; sx[nn][kk + 1] = a.y; sx[nn][kk + 2] = b.x; sx[nn][kk + 3] = b.y;
    }
    __syncthreads();
    int nloc = t >> 2;
    int c0 = (t & 3) * 8;
    float acc[8];
#pragma unroll
    for (int j = 0; j < 8; ++j) acc[j] = 0.f;
#pragma unroll 4
    for (int k = 0; k < HC1; ++k) {
        float xv = sx[nloc][k];
        float4 wa = *(float4*)&sw[k][c0];
        float4 wb = *(float4*)&sw[k][c0 + 4];
        acc[0] += xv * wa.x; acc[1] += xv * wa.y; acc[2] += xv * wa.z; acc[3] += xv * wa.w;
        acc[4] += xv * wb.x; acc[5] += xv * wb.y; acc[6] += xv * wb.z; acc[7] += xv * wb.w;
    }
    int n = base + nloc;
    if (n < N) {
#pragma unroll
        for (int j = 0; j < 4; ++j)
            h2h[(size_t)n * 16 + (c0 >> 1) + j] = __floats2half2_rn(acc[2 * j], acc[2 * j + 1]);
        float ps = 0.f, pd = 0.f;
#pragma unroll
        for (int j = 0; j < 8; ++j) {
            ps += acc[j] * att_s[c0 + j];
            pd += acc[j] * att_d[c0 + j];
        }
        ps += __shfl_down(ps, 1, 64); ps += __shfl_down(ps, 2, 64);
        pd += __shfl_down(pd, 1, 64); pd += __shfl_down(pd, 2, 64);
        if ((t & 3) == 0) { as2[n] = ps; ad2[n] = pd; }
    }
}

// ---- GAT2 aggregation: one wave per dst; 16 edge-slots x 4 lanes x float4,
//      32 edges in flight; elist NT, out2 NT-store ----
__global__ void k_agg2(const int* __restrict__ offsets, const int* __restrict__ elist,
                       const float* __restrict__ as2, const float* __restrict__ ad2,
                       const float4* __restrict__ h2q, const float* __restrict__ b2,
                       int N, float* __restrict__ out2) {
    int wave = threadIdx.x >> 6;
    int lane = threadIdx.x & 63;
    int n = blockIdx.x * 4 + wave;
    if (n >= N) return;
    int slot = lane >> 2, chunk = lane & 3;
    int lo = offsets[n], hi = offsets[n + 1];
    float ad = ad2[n];
    float acc[8];
#pragma unroll
    for (int j = 0; j < 8; ++j) acc[j] = 0.f;
    float sumw = 0.f;
    for (int e0 = lo; e0 < hi; e0 += 32) {
        int eA = e0 + slot, eB = e0 + 16 + slot;
        bool okA = eA < hi, okB = eB < hi;
        int sA = ntl_i(elist + (okA ? eA : lo));
        int sB = ntl_i(elist + (okB ? eB : lo));
        float zA = as2[sA];
        float zB = as2[sB];
        float4 vA = h2q[(size_t)sA * 4 + chunk];
        float4 vB = h2q[(size_t)sB * 4 + chunk];
        float wA = okA ? lrelu_exp(zA + ad) : 0.f;
        float wB = okB ? lrelu_exp(zB + ad) : 0.f;
        const __half2* hA = (const __half2*)&vA;
        const __half2* hB = (const __half2*)&vB;
#pragma unroll
        for (int j = 0; j < 4; ++j) {
            float2 fA = __half22float2(hA[j]);
            float2 fB = __half22float2(hB[j]);
            acc[2 * j]     += wA * fA.x + wB * fB.x;
            acc[2 * j + 1] += wA * fA.y + wB * fB.y;
        }
        sumw += wA + wB;
    }
#pragma unroll
    for (int j = 0; j < 8; ++j) {
        acc[j] += __shfl_xor(acc[j], 4, 64);
        acc[j] += __shfl_xor(acc[j], 8, 64);
        acc[j] += __shfl_xor(acc[j], 16, 64);
        acc[j] += __shfl_xor(acc[j], 32, 64);
    }
    sumw += __shfl_xor(sumw, 4, 64);
    sumw += __shfl_xor(sumw, 8, 64);
    sumw += __shfl_xor(sumw, 16, 64);
    sumw += __shfl_xor(sumw, 32, 64);
    if (slot == 0) {
        float inv = 1.f / (sumw + 1e-16f);
        float4 ba = ((const float4*)b2)[2 * chunk];
        float4 bb = ((const float4*)b2)[2 * chunk + 1];
        float o[8];
        o[0] = acc[0] * inv + ba.x; o[1] = acc[1] * inv + ba.y;
        o[2] = acc[2] * inv + ba.z; o[3] = acc[3] * inv + ba.w;
        o[4] = acc[4] * inv + bb.x; o[5] = acc[5] * inv + bb.y;
        o[6] = acc[6] * inv + bb.z; o[7] = acc[7] * inv + bb.w;
#pragma unroll
        for (int j = 0; j < 8; ++j) o[j] = o[j] > 0.f ? o[j] : expm1f(o[j]);
        float* dst = out2 + (size_t)n * C2 + 8 * chunk;
        nts_f4((float4*)dst, make_float4(o[0], o[1], o[2], o[3]));
        nts_f4((float4*)(dst + 4), make_float4(o[4], o[5], o[6], o[7]));
    }
}

// ---- mean-pool per graph + MLP head ----
__global__ void k_pool(const float* __restrict__ out2, const int* __restrict__ batch,
                       int N, const float* __restrict__ Wh1, const float* __restrict__ bh1,
                       const float* __restrict__ Wh2, const float* __restrict__ bh2,
                       float* __restrict__ out) {
    int g = blockIdx.x;
    int t = threadIdx.x;
    __shared__ int sb[2];
    __shared__ float pooled[C2];
    __shared__ float red[256];
    if (t < 2) {
        int target = g + t;
        int lo = 0, hi = N;
        while (lo < hi) { int mid = (lo + hi) >> 1; if (batch[mid] < target) lo = mid + 1; else hi = mid; }
        sb[t] = lo;
    }
    __syncthreads();
    int lo = sb[0], hi = sb[1];
    int c = t & 31, grp = t >> 5;
    float part = 0.f;
    for (int n = lo + grp; n < hi; n += 8) part += ntl_f(out2 + n * C2 + c);
    red[t] = part;
    __syncthreads();
    if (t < 128) red[t] += red[t + 128];
    __syncthreads();
    if (t < 64) red[t] += red[t + 64];
    __syncthreads();
    if (t < 32) {
        red[t] += red[t + 32];
        float cnt = (float)(hi - lo);
        pooled[t] = red[t] / fmaxf(cnt, 1.f);
    }
    __syncthreads();
    float hval = 0.f;
    if (t < HID) {
        float a = bh1[t];
#pragma unroll
        for (int cc = 0; cc < C2; ++cc) a += pooled[cc] * Wh1[cc * HID + t];
        hval = fmaxf(a, 0.f) * Wh2[t];
    }
    if (t < 64) {
        for (int o = 32; o > 0; o >>= 1) hval += __shfl_down(hval, o, 64);
        if (t == 0) out[g] = hval + bh2[0];
    }
}

extern "C" void kernel_launch(void* const* d_in, const int* in_sizes, int n_in,
                              void* d_out, int out_size, void* d_ws, size_t ws_size,
                              hipStream_t stream) {
    const float* x    = (const float*)d_in[0];
    const int*   ei   = (const int*)d_in[1];
    const int*   batch= (const int*)d_in[2];
    const float* W1   = (const float*)d_in[3];
    const float* aS1  = (const float*)d_in[4];
    const float* aD1  = (const float*)d_in[5];
    const float* b1   = (const float*)d_in[6];
    const float* W2   = (const float*)d_in[7];
    const float* aS2  = (const float*)d_in[8];
    const float* aD2  = (const float*)d_in[9];
    const float* b2   = (const float*)d_in[10];
    const float* Wh1  = (const float*)d_in[11];
    const float* bh1  = (const float*)d_in[12];
    const float* Wh2  = (const float*)d_in[13];
    const float* bh2  = (const float*)d_in[14];
    float* out = (float*)d_out;

    int N = in_sizes[2];
    int E = in_sizes[1] / 2;
    int M = E + N;
    int G = out_size;
    int nb = (N + SCAN_B - 1) / SCAN_B;
    int npp = (N + NPART - 1) / NPART;

    char* p = (char*)d_ws;
    auto alloc = [&](size_t bytes) -> void* {
        void* r = (void*)p;
        p += (bytes + 255) & ~(size_t)255;
        return r;
    };
    __half2* h1h   = (__half2*)alloc((size_t)N * 64 * 4);   // N x 128 fp16
    __half2* out1h = (__half2*)alloc((size_t)N * 64 * 4);
    __half2* h2h   = (__half2*)alloc((size_t)N * 16 * 4);   // N x 32 fp16
    float* as1     = (float*)alloc((size_t)N * NH1 * 4);
    float* ad1     = (float*)alloc((size_t)N * NH1 * 4);
    float* as2     = (float*)alloc((size_t)N * 4);
    float* ad2     = (float*)alloc((size_t)N * 4);
    float* out2    = (float*)alloc((size_t)N * C2 * 4);
    int*   deg     = (int*)alloc((size_t)N * 4);
    int*   offsets = (int*)alloc((size_t)(N + 1) * 4);
    int*   cursor  = (int*)alloc((size_t)(N + 1) * 4);
    int*   elist   = (int*)alloc((size_t)M * 4);
    int*   tmp     = (int*)alloc((size_t)N * 4);
    int*   bsum    = (int*)alloc((size_t)nb * 4);
    int*   boff    = (int*)alloc((size_t)nb * 4);

    hipMemsetAsync(deg, 0, (size_t)N * 4, stream);
    k_deg<<<NPART * 128, 256, 0, stream>>>(ei, E, N, npp, deg);
    k_scan1<<<nb, SCAN_B, 0, stream>>>(deg, N, tmp, bsum);
    k_scan2<<<1, 1024, 0, stream>>>(bsum, nb, boff, offsets, N);
    k_scan3<<<nb, SCAN_B, 0, stream>>>(deg, tmp, boff, N, offsets, cursor);
    k_lin1<<<(N + 3) / 4, 256, 0, stream>>>(x, (const float2*)W1, (const float2*)aS1,
                                            (const float2*)aD1, N, h1h, as1, ad1);
    k_scatter<<<NPART * 128, 256, 0, stream>>>(ei, E, N, npp, cursor, elist);
    k_agg1<<<(N + 3) / 4, 256, 0, stream>>>(offsets, elist, as1, ad1,
                                            (const float4*)h1h, b1, N, (float4*)out1h);
    k_lin2<<<(N + TN - 1) / TN, 256, 0, stream>>>(out1h, W2, aS2, aD2, N, h2h, as2, ad2);
    k_agg2<<<(N + 3) / 4, 256, 0, stream>>>(offsets, elist, as2, ad2,
                                            (const float4*)h2h, b2, N, out2);
    k_pool<<<G, 256, 0, stream>>>(out2, batch, N, Wh1, bh1, Wh2, bh2, out);
}

// Round 7
// 294.382 us; speedup vs baseline: 1.4415x; 1.4415x over previous
//
#include <hip/hip_runtime.h>
#include <hip/hip_fp16.h>
#include <math.h>

#define IN_CH 16
#define HC1 128   // H1*C1
#define NH1 4
#define C2 32
#define HID 64
#define NEG 0.2f
#define CAP 10240     // per-bucket capacity (mean ~8450, +20 sigma)
#define CHUNK 4096    // edges per k_bucket block

__device__ __forceinline__ float lrelu_exp(float z) {
    float lr = z > 0.f ? z : NEG * z;
    return expf(lr);
}

// ---- CSR build via bucketed counting sort ----
// Phase A: stream edges, append (src<<8 | dstLocal) to bucket[dst>>8].
// LDS histogram per 4096-edge chunk -> 256 global atomics per chunk.
__global__ void k_bucket(const int* __restrict__ ei, int E, int N, int nbk,
                         int* __restrict__ cursors, int* __restrict__ buckets) {
    __shared__ int cnt[256];
    __shared__ int base[256];
    __shared__ int pos[256];
    int t = threadIdx.x;
    int c0 = blockIdx.x * CHUNK;
    int M = E + N;
    cnt[t] = 0;
    pos[t] = 0;
    __syncthreads();
    int srcv[16], dstv[16];
#pragma unroll
    for (int k = 0; k < 16; ++k) {
        int i = c0 + k * 256 + t;
        int s = -1, d = -1;
        if (i < M) {
            if (i < E) { s = ei[i]; d = ei[E + i]; }
            else       { s = d = i - E; }
            atomicAdd(&cnt[d >> 8], 1);
        }
        srcv[k] = s; dstv[k] = d;
    }
    __syncthreads();
    if (cnt[t] > 0) base[t] = atomicAdd(&cursors[t], cnt[t]);
    __syncthreads();
#pragma unroll
    for (int k = 0; k < 16; ++k) {
        int d = dstv[k];
        if (d >= 0) {
            int b = d >> 8;
            int p = base[b] + atomicAdd(&pos[b], 1);
            buckets[b * CAP + p] = (srcv[k] << 8) | (d & 255);
        }
    }
}

// Phase A2: exclusive scan of bucket counts -> global bucket bases.
__global__ void k_bscan(const int* __restrict__ cursors, int nbk,
                        int* __restrict__ bbase, int* __restrict__ offsets,
                        int N, int M) {
    __shared__ int s[256];
    int t = threadIdx.x;
    int v = (t < nbk) ? cursors[t] : 0;
    s[t] = v;
    __syncthreads();
    for (int o = 1; o < 256; o <<= 1) {
        int a = (t >= o) ? s[t - o] : 0;
        __syncthreads();
        s[t] += a;
        __syncthreads();
    }
    bbase[t] = s[t] - v;
    if (t == 0) offsets[N] = M;
}

// Phase B: one block per bucket. LDS deg/scan/cursor over the bucket's 256
// nodes; scatter src ids into the bucket's contiguous elist region (~33KB,
// single-writer -> dirty lines merge in L2); offsets written coalesced.
__global__ void k_build(const int* __restrict__ buckets, const int* __restrict__ cursors,
                        const int* __restrict__ bbase, int N,
                        int* __restrict__ offsets, int* __restrict__ elist) {
    __shared__ int deg[256];
    __shared__ int sc[256];
    __shared__ int cur[256];
    int b = blockIdx.x, t = threadIdx.x;
    int n0 = b << 8;
    int cnt = cursors[b];
    int gbase = bbase[b];
    const int* bk = buckets + b * CAP;
    deg[t] = 0;
    __syncthreads();
    for (int i = t; i < cnt; i += 256) atomicAdd(&deg[bk[i] & 255], 1);
    __syncthreads();
    int v = deg[t];
    sc[t] = v;
    __syncthreads();
    for (int o = 1; o < 256; o <<= 1) {
        int a = (t >= o) ? sc[t - o] : 0;
        __syncthreads();
        sc[t] += a;
        __syncthreads();
    }
    int excl = sc[t] - v;
    cur[t] = excl;
    if (n0 + t < N) offsets[n0 + t] = gbase + excl;
    __syncthreads();
    for (int i = t; i < cnt; i += 256) {
        int e = bk[i];
        int p = atomicAdd(&cur[e & 255], 1);
        elist[gbase + p] = e >> 8;
    }
}

// ---- GAT1 linear + logits: one wave per node, 2 channels/lane ----
__global__ void k_lin1(const float* __restrict__ x, const float2* __restrict__ W1v,
                       const float2* __restrict__ att_s2, const float2* __restrict__ att_d2,
                       int N, __half2* __restrict__ h1h, float* __restrict__ as1, float* __restrict__ ad1) {
    int wave = threadIdx.x >> 6;
    int lane = threadIdx.x & 63;
    int n = blockIdx.x * 4 + wave;
    if (n >= N) return;
    float xv = x[n * IN_CH + (lane & 15)];
    float ax = 0.f, ay = 0.f;
#pragma unroll
    for (int k = 0; k < IN_CH; ++k) {
        float xk = __shfl(xv, k, 16);
        float2 w = W1v[k * 64 + lane];
        ax += xk * w.x;
        ay += xk * w.y;
    }
    h1h[(size_t)n * 64 + lane] = __floats2half2_rn(ax, ay);
    float2 s2 = att_s2[lane], d2 = att_d2[lane];
    float vs = ax * s2.x + ay * s2.y;
    float vd = ax * d2.x + ay * d2.y;
#pragma unroll
    for (int o = 1; o < 16; o <<= 1) {
        vs += __shfl_xor(vs, o, 64);
        vd += __shfl_xor(vd, o, 64);
    }
    if ((lane & 15) == 0) {
        as1[n * NH1 + (lane >> 4)] = vs;
        ad1[n * NH1 + (lane >> 4)] = vd;
    }
}

// ---- GAT1 aggregation: one wave per dst; 4 edge-slots x 16 lanes x float4,
//      16 edges in flight ----
__global__ void k_agg1(const int* __restrict__ offsets, const int* __restrict__ elist,
                       const float* __restrict__ as1, const float* __restrict__ ad1,
                       const float4* __restrict__ h1q, const float* __restrict__ b1,
                       int N, float4* __restrict__ out1q) {
    int wave = threadIdx.x >> 6;
    int lane = threadIdx.x & 63;
    int n = blockIdx.x * 4 + wave;
    if (n >= N) return;
    int slot = lane >> 4, chunk = lane & 15, head = chunk >> 2;
    int lo = offsets[n], hi = offsets[n + 1];
    float adh = ad1[n * NH1 + head];
    float acc[8];
#pragma unroll
    for (int j = 0; j < 8; ++j) acc[j] = 0.f;
    float sumw = 0.f;
#pragma unroll 2
    for (int e0 = lo; e0 < hi; e0 += 8) {
        int eA = e0 + slot, eB = e0 + 4 + slot;
        bool okA = eA < hi, okB = eB < hi;
        int sA = elist[okA ? eA : lo];
        int sB = elist[okB ? eB : lo];
        float zA = as1[sA * NH1 + head];
        float zB = as1[sB * NH1 + head];
        float4 vA = h1q[(size_t)sA * 16 + chunk];
        float4 vB = h1q[(size_t)sB * 16 + chunk];
        float wA = okA ? lrelu_exp(zA + adh) : 0.f;
        float wB = okB ? lrelu_exp(zB + adh) : 0.f;
        const __half2* hA = (const __half2*)&vA;
        const __half2* hB = (const __half2*)&vB;
#pragma unroll
        for (int j = 0; j < 4; ++j) {
            float2 fA = __half22float2(hA[j]);
            float2 fB = __half22float2(hB[j]);
            acc[2 * j]     += wA * fA.x + wB * fB.x;
            acc[2 * j + 1] += wA * fA.y + wB * fB.y;
        }
        sumw += wA + wB;
    }
#pragma unroll
    for (int j = 0; j < 8; ++j) {
        acc[j] += __shfl_xor(acc[j], 16, 64);
        acc[j] += __shfl_xor(acc[j], 32, 64);
    }
    sumw += __shfl_xor(sumw, 16, 64);
    sumw += __shfl_xor(sumw, 32, 64);
    if (slot == 0) {
        float inv = 1.f / (sumw + 1e-16f);
        float4 ba = ((const float4*)b1)[2 * chunk];
        float4 bb = ((const float4*)b1)[2 * chunk + 1];
        float o[8];
        o[0] = acc[0] * inv + ba.x; o[1] = acc[1] * inv + ba.y;
        o[2] = acc[2] * inv + ba.z; o[3] = acc[3] * inv + ba.w;
        o[4] = acc[4] * inv + bb.x; o[5] = acc[5] * inv + bb.y;
        o[6] = acc[6] * inv + bb.z; o[7] = acc[7] * inv + bb.w;
#pragma unroll
        for (int j = 0; j < 8; ++j) o[j] = o[j] > 0.f ? o[j] : expm1f(o[j]);
        float4 pk;
        __half2* ph = (__half2*)&pk;
        ph[0] = __floats2half2_rn(o[0], o[1]);
        ph[1] = __floats2half2_rn(o[2], o[3]);
        ph[2] = __floats2half2_rn(o[4], o[5]);
        ph[3] = __floats2half2_rn(o[6], o[7]);
        out1q[(size_t)n * 16 + chunk] = pk;
    }
}

// ---- GAT2 linear: LDS-tiled GEMM [N,128](fp16) x [128,32] + logits ----
#define TN 64
__global__ void k_lin2(const __half2* __restrict__ out1h, const float* __restrict__ W2,
                       const float* __restrict__ att_s, const float* __restrict__ att_d,
                       int N, __half2* __restrict__ h2h, float* __restrict__ as2, float* __restrict__ ad2) {
    __shared__ float sx[TN][HC1 + 1];
    __shared__ float sw[HC1][C2];
    int t = threadIdx.x;  // 256
    int base = blockIdx.x * TN;
    int lim = (N - base) * HC1;
    for (int i = t * 4; i < HC1 * C2; i += 1024) {
        float4 v = *(const float4*)(W2 + i);
        sw[i >> 5][i & 31] = v.x;
        sw[i >> 5][(i & 31) + 1] = v.y;
        sw[i >> 5][(i & 31) + 2] = v.z;
        sw[i >> 5][(i & 31) + 3] = v.w;
    }
    for (int i = t * 4; i < TN * HC1; i += 1024) {
        float2 a = make_float2(0.f, 0.f), b = make_float2(0.f, 0.f);
        if (i < lim) {
            size_t idx = ((size_t)base * HC1 + i) >> 1;
            a = __half22float2(out1h[idx]);
            b = __half22float2(out1h[idx + 1]);
        }
        int nn = i >> 7, kk = i & 127;
        sx[nn][kk] = a.x; sx[nn][kk + 1] = a.y; sx[nn][kk + 2] = b.x; sx[nn][kk + 3] = b.y;
    }
    __syncthreads();
    int nloc = t >> 2;
    int c0 = (t & 3) * 8;
    float acc[8];
#pragma unroll
    for (int j = 0; j < 8; ++j) acc[j] = 0.f;
#pragma unroll 4
    for (int k = 0; k < HC1; ++k) {
        float xv = sx[nloc][k];
        float4 wa = *(float4*)&sw[k][c0];
        float4 wb = *(float4*)&sw[k][c0 + 4];
        acc[0] += xv * wa.x; acc[1] += xv * wa.y; acc[2] += xv * wa.z; acc[3] += xv * wa.w;
        acc[4] += xv * wb.x; acc[5] += xv * wb.y; acc[6] += xv * wb.z; acc[7] += xv * wb.w;
    }
    int n = base + nloc;
    if (n < N) {
#pragma unroll
        for (int j = 0; j < 4; ++j)
            h2h[(size_t)n * 16 + (c0 >> 1) + j] = __floats2half2_rn(acc[2 * j], acc[2 * j + 1]);
        float ps = 0.f, pd = 0.f;
#pragma unroll
        for (int j = 0; j < 8; ++j) {
            ps += acc[j] * att_s[c0 + j];
            pd += acc[j] * att_d[c0 + j];
        }
        ps += __shfl_down(ps, 1, 64); ps += __shfl_down(ps, 2, 64);
        pd += __shfl_down(pd, 1, 64); pd += __shfl_down(pd, 2, 64);
        if ((t & 3) == 0) { as2[n] = ps; ad2[n] = pd; }
    }
}

// ---- GAT2 aggregation: one wave per dst; 16 edge-slots x 4 lanes x float4,
//      32 edges in flight ----
__global__ void k_agg2(const int* __restrict__ offsets, const int* __restrict__ elist,
                       const float* __restrict__ as2, const float* __restrict__ ad2,
                       const float4* __restrict__ h2q, const float* __restrict__ b2,
                       int N, float* __restrict__ out2) {
    int wave = threadIdx.x >> 6;
    int lane = threadIdx.x & 63;
    int n = blockIdx.x * 4 + wave;
    if (n >= N) return;
    int slot = lane >> 2, chunk = lane & 3;
    int lo = offsets[n], hi = offsets[n + 1];
    float ad = ad2[n];
    float acc[8];
#pragma unroll
    for (int j = 0; j < 8; ++j) acc[j] = 0.f;
    float sumw = 0.f;
    for (int e0 = lo; e0 < hi; e0 += 32) {
        int eA = e0 + slot, eB = e0 + 16 + slot;
        bool okA = eA < hi, okB = eB < hi;
        int sA = elist[okA ? eA : lo];
        int sB = elist[okB ? eB : lo];
        float zA = as2[sA];
        float zB = as2[sB];
        float4 vA = h2q[(size_t)sA * 4 + chunk];
        float4 vB = h2q[(size_t)sB * 4 + chunk];
        float wA = okA ? lrelu_exp(zA + ad) : 0.f;
        float wB = okB ? lrelu_exp(zB + ad) : 0.f;
        const __half2* hA = (const __half2*)&vA;
        const __half2* hB = (const __half2*)&vB;
#pragma unroll
        for (int j = 0; j < 4; ++j) {
            float2 fA = __half22float2(hA[j]);
            float2 fB = __half22float2(hB[j]);
            acc[2 * j]     += wA * fA.x + wB * fB.x;
            acc[2 * j + 1] += wA * fA.y + wB * fB.y;
        }
        sumw += wA + wB;
    }
#pragma unroll
    for (int j = 0; j < 8; ++j) {
        acc[j] += __shfl_xor(acc[j], 4, 64);
        acc[j] += __shfl_xor(acc[j], 8, 64);
        acc[j] += __shfl_xor(acc[j], 16, 64);
        acc[j] += __shfl_xor(acc[j], 32, 64);
    }
    sumw += __shfl_xor(sumw, 4, 64);
    sumw += __shfl_xor(sumw, 8, 64);
    sumw += __shfl_xor(sumw, 16, 64);
    sumw += __shfl_xor(sumw, 32, 64);
    if (slot == 0) {
        float inv = 1.f / (sumw + 1e-16f);
        float4 ba = ((const float4*)b2)[2 * chunk];
        float4 bb = ((const float4*)b2)[2 * chunk + 1];
        float o[8];
        o[0] = acc[0] * inv + ba.x; o[1] = acc[1] * inv + ba.y;
        o[2] = acc[2] * inv + ba.z; o[3] = acc[3] * inv + ba.w;
        o[4] = acc[4] * inv + bb.x; o[5] = acc[5] * inv + bb.y;
        o[6] = acc[6] * inv + bb.z; o[7] = acc[7] * inv + bb.w;
#pragma unroll
        for (int j = 0; j < 8; ++j) o[j] = o[j] > 0.f ? o[j] : expm1f(o[j]);
        float* dst = out2 + (size_t)n * C2 + 8 * chunk;
        *(float4*)dst = make_float4(o[0], o[1], o[2], o[3]);
        *(float4*)(dst + 4) = make_float4(o[4], o[5], o[6], o[7]);
    }
}

// ---- mean-pool per graph + MLP head ----
__global__ void k_pool(const float* __restrict__ out2, const int* __restrict__ batch,
                       int N, const float* __restrict__ Wh1, const float* __restrict__ bh1,
                       const float* __restrict__ Wh2, const float* __restrict__ bh2,
                       float* __restrict__ out) {
    int g = blockIdx.x;
    int t = threadIdx.x;
    __shared__ int sb[2];
    __shared__ float pooled[C2];
    __shared__ float red[256];
    if (t < 2) {
        int target = g + t;
        int lo = 0, hi = N;
        while (lo < hi) { int mid = (lo + hi) >> 1; if (batch[mid] < target) lo = mid + 1; else hi = mid; }
        sb[t] = lo;
    }
    __syncthreads();
    int lo = sb[0], hi = sb[1];
    int c = t & 31, grp = t >> 5;
    float part = 0.f;
    for (int n = lo + grp; n < hi; n += 8) part += out2[n * C2 + c];
    red[t] = part;
    __syncthreads();
    if (t < 128) red[t] += red[t + 128];
    __syncthreads();
    if (t < 64) red[t] += red[t + 64];
    __syncthreads();
    if (t < 32) {
        red[t] += red[t + 32];
        float cnt = (float)(hi - lo);
        pooled[t] = red[t] / fmaxf(cnt, 1.f);
    }
    __syncthreads();
    float hval = 0.f;
    if (t < HID) {
        float a = bh1[t];
#pragma unroll
        for (int cc = 0; cc < C2; ++cc) a += pooled[cc] * Wh1[cc * HID + t];
        hval = fmaxf(a, 0.f) * Wh2[t];
    }
    if (t < 64) {
        for (int o = 32; o > 0; o >>= 1) hval += __shfl_down(hval, o, 64);
        if (t == 0) out[g] = hval + bh2[0];
    }
}

extern "C" void kernel_launch(void* const* d_in, const int* in_sizes, int n_in,
                              void* d_out, int out_size, void* d_ws, size_t ws_size,
                              hipStream_t stream) {
    const float* x    = (const float*)d_in[0];
    const int*   ei   = (const int*)d_in[1];
    const int*   batch= (const int*)d_in[2];
    const float* W1   = (const float*)d_in[3];
    const float* aS1  = (const float*)d_in[4];
    const float* aD1  = (const float*)d_in[5];
    const float* b1   = (const float*)d_in[6];
    const float* W2   = (const float*)d_in[7];
    const float* aS2  = (const float*)d_in[8];
    const float* aD2  = (const float*)d_in[9];
    const float* b2   = (const float*)d_in[10];
    const float* Wh1  = (const float*)d_in[11];
    const float* bh1  = (const float*)d_in[12];
    const float* Wh2  = (const float*)d_in[13];
    const float* bh2  = (const float*)d_in[14];
    float* out = (float*)d_out;

    int N = in_sizes[2];
    int E = in_sizes[1] / 2;
    int M = E + N;
    int G = out_size;
    int nbk = (N + 255) >> 8;           // buckets of 256 nodes

    char* p = (char*)d_ws;
    auto alloc = [&](size_t bytes) -> void* {
        void* r = (void*)p;
        p += (bytes + 255) & ~(size_t)255;
        return r;
    };
    __half2* h1h   = (__half2*)alloc((size_t)N * 64 * 4);   // N x 128 fp16
    __half2* out1h = (__half2*)alloc((size_t)N * 64 * 4);
    __half2* h2h   = (__half2*)alloc((size_t)N * 16 * 4);   // N x 32 fp16
    float* as1     = (float*)alloc((size_t)N * NH1 * 4);
    float* ad1     = (float*)alloc((size_t)N * NH1 * 4);
    float* as2     = (float*)alloc((size_t)N * 4);
    float* ad2     = (float*)alloc((size_t)N * 4);
    float* out2    = (float*)alloc((size_t)N * C2 * 4);
    int*   offsets = (int*)alloc((size_t)(N + 1) * 4);
    int*   elist   = (int*)alloc((size_t)M * 4);
    int*   cursors = (int*)alloc(256 * 4);
    int*   bbase   = (int*)alloc(256 * 4);
    int*   buckets = (int*)alloc((size_t)nbk * CAP * 4);

    hipMemsetAsync(cursors, 0, 256 * 4, stream);
    k_bucket<<<(M + CHUNK - 1) / CHUNK, 256, 0, stream>>>(ei, E, N, nbk, cursors, buckets);
    k_bscan<<<1, 256, 0, stream>>>(cursors, nbk, bbase, offsets, N, M);
    k_build<<<nbk, 256, 0, stream>>>(buckets, cursors, bbase, N, offsets, elist);
    k_lin1<<<(N + 3) / 4, 256, 0, stream>>>(x, (const float2*)W1, (const float2*)aS1,
                                            (const float2*)aD1, N, h1h, as1, ad1);
    k_agg1<<<(N + 3) / 4, 256, 0, stream>>>(offsets, elist, as1, ad1,
                                            (const float4*)h1h, b1, N, (float4*)out1h);
    k_lin2<<<(N + TN - 1) / TN, 256, 0, stream>>>(out1h, W2, aS2, aD2, N, h2h, as2, ad2);
    k_agg2<<<(N + 3) / 4, 256, 0, stream>>>(offsets, elist, as2, ad2,
                                            (const float4*)h2h, b2, N, out2);
    k_pool<<<G, 256, 0, stream>>>(out2, batch, N, Wh1, bh1, Wh2, bh2, out);
}

// Round 8
// 283.623 us; speedup vs baseline: 1.4962x; 1.0379x over previous
//
#include <hip/hip_runtime.h>
#include <hip/hip_fp16.h>
#include <math.h>

#define IN_CH 16
#define HC1 128   // H1*C1
#define NH1 4
#define C2 32
#define HID 64
#define NEG 0.2f
#define CAP 10240     // per-bucket capacity (mean ~8450, +20 sigma)
#define CHUNK 4096    // edges per bucket block

__device__ __forceinline__ float lrelu_exp_fast(float z) {
    float lr = fmaxf(z, NEG * z);   // leaky-relu via max (exact for neg_slope<1)
    return __expf(lr);
}

// ---- Fused front: bucket-append (blocks [0,nchunk)) + GAT1 linear (rest) ----
__global__ void k_front(const int* __restrict__ ei, int E, int N, int nchunk,
                        int* __restrict__ cursors, int* __restrict__ buckets,
                        const float* __restrict__ x, const float2* __restrict__ W1v,
                        const float2* __restrict__ att_s2, const float2* __restrict__ att_d2,
                        __half2* __restrict__ h1h, float* __restrict__ as1, float* __restrict__ ad1) {
    int bid = blockIdx.x;
    if (bid < nchunk) {
        // ---- bucket phase: append (src<<8|dstLocal) to bucket[dst>>8] ----
        __shared__ int cnt[256];
        __shared__ int base[256];
        __shared__ int pos[256];
        int t = threadIdx.x;
        int c0 = bid * CHUNK;
        int M = E + N;
        cnt[t] = 0;
        pos[t] = 0;
        __syncthreads();
        int srcv[16], dstv[16];
#pragma unroll
        for (int k = 0; k < 16; ++k) {
            int i = c0 + k * 256 + t;
            int s = -1, d = -1;
            if (i < M) {
                if (i < E) { s = ei[i]; d = ei[E + i]; }
                else       { s = d = i - E; }
                atomicAdd(&cnt[d >> 8], 1);
            }
            srcv[k] = s; dstv[k] = d;
        }
        __syncthreads();
        if (cnt[t] > 0) base[t] = atomicAdd(&cursors[t], cnt[t]);
        __syncthreads();
#pragma unroll
        for (int k = 0; k < 16; ++k) {
            int d = dstv[k];
            if (d >= 0) {
                int b = d >> 8;
                int p = base[b] + atomicAdd(&pos[b], 1);
                buckets[b * CAP + p] = (srcv[k] << 8) | (d & 255);
            }
        }
    } else {
        // ---- GAT1 linear + logits: one wave per node, 2 channels/lane ----
        int wave = threadIdx.x >> 6;
        int lane = threadIdx.x & 63;
        int n = (bid - nchunk) * 4 + wave;
        if (n >= N) return;
        float xv = x[n * IN_CH + (lane & 15)];
        float ax = 0.f, ay = 0.f;
#pragma unroll
        for (int k = 0; k < IN_CH; ++k) {
            float xk = __shfl(xv, k, 16);
            float2 w = W1v[k * 64 + lane];
            ax += xk * w.x;
            ay += xk * w.y;
        }
        h1h[(size_t)n * 64 + lane] = __floats2half2_rn(ax, ay);
        float2 s2 = att_s2[lane], d2 = att_d2[lane];
        float vs = ax * s2.x + ay * s2.y;
        float vd = ax * d2.x + ay * d2.y;
#pragma unroll
        for (int o = 1; o < 16; o <<= 1) {
            vs += __shfl_xor(vs, o, 64);
            vd += __shfl_xor(vd, o, 64);
        }
        if ((lane & 15) == 0) {
            as1[n * NH1 + (lane >> 4)] = vs;
            ad1[n * NH1 + (lane >> 4)] = vd;
        }
    }
}

// ---- CSR build: one block per bucket; inline scan of bucket counts ----
__global__ void k_build(const int* __restrict__ buckets, const int* __restrict__ cursors,
                        int N, int M,
                        int* __restrict__ offsets, int* __restrict__ elist) {
    __shared__ int sc[256];
    __shared__ int deg[256];
    __shared__ int cur[256];
    int b = blockIdx.x, t = threadIdx.x;
    // exclusive prefix of bucket counts (cursors[t]=0 for t>=nbk)
    int cv = cursors[t];
    sc[t] = cv;
    __syncthreads();
    for (int o = 1; o < 256; o <<= 1) {
        int a = (t >= o) ? sc[t - o] : 0;
        __syncthreads();
        sc[t] += a;
        __syncthreads();
    }
    int cnt = cursors[b];
    int gbase = sc[b] - cnt;
    int n0 = b << 8;
    const int* bk = buckets + b * CAP;
    deg[t] = 0;
    if (b == 0 && t == 0) offsets[N] = M;
    __syncthreads();
    for (int i = t; i < cnt; i += 256) atomicAdd(&deg[bk[i] & 255], 1);
    __syncthreads();
    int v = deg[t];
    sc[t] = v;
    __syncthreads();
    for (int o = 1; o < 256; o <<= 1) {
        int a = (t >= o) ? sc[t - o] : 0;
        __syncthreads();
        sc[t] += a;
        __syncthreads();
    }
    int excl = sc[t] - v;
    cur[t] = excl;
    if (n0 + t < N) offsets[n0 + t] = gbase + excl;
    __syncthreads();
    for (int i = t; i < cnt; i += 256) {
        int e = bk[i];
        int p = atomicAdd(&cur[e & 255], 1);
        elist[gbase + p] = e >> 8;
    }
}

// ---- GAT1 aggregation: one wave per dst; 4 edge-slots x 16 lanes x float4,
//      16 edges in flight; 32-bit byte offsets + fast exp ----
__global__ void k_agg1(const int* __restrict__ offsets, const int* __restrict__ elist,
                       const char* __restrict__ as1b, const float* __restrict__ ad1,
                       const char* __restrict__ h1b, const float* __restrict__ b1,
                       int N, float4* __restrict__ out1q) {
    int wave = threadIdx.x >> 6;
    int lane = threadIdx.x & 63;
    int n = blockIdx.x * 4 + wave;
    if (n >= N) return;
    int slot = lane >> 4, chunk = lane & 15, head = chunk >> 2;
    int lo = offsets[n], hi = offsets[n + 1];
    float adh = ad1[n * NH1 + head];
    int coff = chunk << 4;   // byte offset within 256B h1 row
    int hoff = head << 2;    // byte offset within 16B as1 row
    float acc[8];
#pragma unroll
    for (int j = 0; j < 8; ++j) acc[j] = 0.f;
    float sumw = 0.f;
    for (int e0 = lo; e0 < hi; e0 += 16) {
        int s[4]; bool ok[4]; float z[4]; float4 v[4]; float w[4];
#pragma unroll
        for (int u = 0; u < 4; ++u) {
            int ee = e0 + 4 * u + slot;
            ok[u] = ee < hi;
            s[u] = elist[ok[u] ? ee : lo];
        }
#pragma unroll
        for (int u = 0; u < 4; ++u) {
            z[u] = *(const float*)(as1b + ((s[u] << 4) + hoff));
            v[u] = *(const float4*)(h1b + ((s[u] << 8) + coff));
        }
#pragma unroll
        for (int u = 0; u < 4; ++u)
            w[u] = ok[u] ? lrelu_exp_fast(z[u] + adh) : 0.f;
#pragma unroll
        for (int u = 0; u < 4; ++u) {
            const __half2* hv = (const __half2*)&v[u];
#pragma unroll
            for (int j = 0; j < 4; ++j) {
                float2 f = __half22float2(hv[j]);
                acc[2 * j]     += w[u] * f.x;
                acc[2 * j + 1] += w[u] * f.y;
            }
            sumw += w[u];
        }
    }
#pragma unroll
    for (int j = 0; j < 8; ++j) {
        acc[j] += __shfl_xor(acc[j], 16, 64);
        acc[j] += __shfl_xor(acc[j], 32, 64);
    }
    sumw += __shfl_xor(sumw, 16, 64);
    sumw += __shfl_xor(sumw, 32, 64);
    if (slot == 0) {
        float inv = 1.f / (sumw + 1e-16f);
        float4 ba = ((const float4*)b1)[2 * chunk];
        float4 bb = ((const float4*)b1)[2 * chunk + 1];
        float o[8];
        o[0] = acc[0] * inv + ba.x; o[1] = acc[1] * inv + ba.y;
        o[2] = acc[2] * inv + ba.z; o[3] = acc[3] * inv + ba.w;
        o[4] = acc[4] * inv + bb.x; o[5] = acc[5] * inv + bb.y;
        o[6] = acc[6] * inv + bb.z; o[7] = acc[7] * inv + bb.w;
#pragma unroll
        for (int j = 0; j < 8; ++j) o[j] = o[j] > 0.f ? o[j] : expm1f(o[j]);
        float4 pk;
        __half2* ph = (__half2*)&pk;
        ph[0] = __floats2half2_rn(o[0], o[1]);
        ph[1] = __floats2half2_rn(o[2], o[3]);
        ph[2] = __floats2half2_rn(o[4], o[5]);
        ph[3] = __floats2half2_rn(o[6], o[7]);
        out1q[(size_t)n * 16 + chunk] = pk;
    }
}

// ---- GAT2 linear: LDS-tiled GEMM [N,128](fp16) x [128,32] + logits ----
#define TN 64
__global__ void k_lin2(const __half2* __restrict__ out1h, const float* __restrict__ W2,
                       const float* __restrict__ att_s, const float* __restrict__ att_d,
                       int N, __half2* __restrict__ h2h, float* __restrict__ as2, float* __restrict__ ad2) {
    __shared__ float sx[TN][HC1 + 1];
    __shared__ float sw[HC1][C2];
    int t = threadIdx.x;  // 256
    int base = blockIdx.x * TN;
    int lim = (N - base) * HC1;
    for (int i = t * 4; i < HC1 * C2; i += 1024) {
        float4 v = *(const float4*)(W2 + i);
        sw[i >> 5][i & 31] = v.x;
        sw[i >> 5][(i & 31) + 1] = v.y;
        sw[i >> 5][(i & 31) + 2] = v.z;
        sw[i >> 5][(i & 31) + 3] = v.w;
    }
    for (int i = t * 4; i < TN * HC1; i += 1024) {
        float2 a = make_float2(0.f, 0.f), b = make_float2(0.f, 0.f);
        if (i < lim) {
            size_t idx = ((size_t)base * HC1 + i) >> 1;
            a = __half22float2(out1h[idx]);
            b = __half22float2(out1h[idx + 1]);
        }
        int nn = i >> 7, kk = i & 127;
        sx[nn][kk] = a.x; sx[nn][kk + 1] = a.y; sx[nn][kk + 2] = b.x; sx[nn][kk + 3] = b.y;
    }
    __syncthreads();
    int nloc = t >> 2;
    int c0 = (t & 3) * 8;
    float acc[8];
#pragma unroll
    for (int j = 0; j < 8; ++j) acc[j] = 0.f;
#pragma unroll 4
    for (int k = 0; k < HC1; ++k) {
        float xv = sx[nloc][k];
        float4 wa = *(float4*)&sw[k][c0];
        float4 wb = *(float4*)&sw[k][c0 + 4];
        acc[0] += xv * wa.x; acc[1] += xv * wa.y; acc[2] += xv * wa.z; acc[3] += xv * wa.w;
        acc[4] += xv * wb.x; acc[5] += xv * wb.y; acc[6] += xv * wb.z; acc[7] += xv * wb.w;
    }
    int n = base + nloc;
    if (n < N) {
#pragma unroll
        for (int j = 0; j < 4; ++j)
            h2h[(size_t)n * 16 + (c0 >> 1) + j] = __floats2half2_rn(acc[2 * j], acc[2 * j + 1]);
        float ps = 0.f, pd = 0.f;
#pragma unroll
        for (int j = 0; j < 8; ++j) {
            ps += acc[j] * att_s[c0 + j];
            pd += acc[j] * att_d[c0 + j];
        }
        ps += __shfl_down(ps, 1, 64); ps += __shfl_down(ps, 2, 64);
        pd += __shfl_down(pd, 1, 64); pd += __shfl_down(pd, 2, 64);
        if ((t & 3) == 0) { as2[n] = ps; ad2[n] = pd; }
    }
}

// ---- GAT2 aggregation: one wave per dst; 16 edge-slots x 4 lanes x float4,
//      32 edges in flight; 32-bit byte offsets + fast exp ----
__global__ void k_agg2(const int* __restrict__ offsets, const int* __restrict__ elist,
                       const char* __restrict__ as2b, const float* __restrict__ ad2,
                       const char* __restrict__ h2b, const float* __restrict__ b2,
                       int N, float* __restrict__ out2) {
    int wave = threadIdx.x >> 6;
    int lane = threadIdx.x & 63;
    int n = blockIdx.x * 4 + wave;
    if (n >= N) return;
    int slot = lane >> 2, chunk = lane & 3;
    int lo = offsets[n], hi = offsets[n + 1];
    float ad = ad2[n];
    int coff = chunk << 4;   // byte offset within 64B h2 row
    float acc[8];
#pragma unroll
    for (int j = 0; j < 8; ++j) acc[j] = 0.f;
    float sumw = 0.f;
    for (int e0 = lo; e0 < hi; e0 += 32) {
        int s[2]; bool ok[2]; float z[2]; float4 v[2]; float w[2];
#pragma unroll
        for (int u = 0; u < 2; ++u) {
            int ee = e0 + 16 * u + slot;
            ok[u] = ee < hi;
            s[u] = elist[ok[u] ? ee : lo];
        }
#pragma unroll
        for (int u = 0; u < 2; ++u) {
            z[u] = *(const float*)(as2b + (s[u] << 2));
            v[u] = *(const float4*)(h2b + ((s[u] << 6) + coff));
        }
#pragma unroll
        for (int u = 0; u < 2; ++u)
            w[u] = ok[u] ? lrelu_exp_fast(z[u] + ad) : 0.f;
#pragma unroll
        for (int u = 0; u < 2; ++u) {
            const __half2* hv = (const __half2*)&v[u];
#pragma unroll
            for (int j = 0; j < 4; ++j) {
                float2 f = __half22float2(hv[j]);
                acc[2 * j]     += w[u] * f.x;
                acc[2 * j + 1] += w[u] * f.y;
            }
            sumw += w[u];
        }
    }
#pragma unroll
    for (int j = 0; j < 8; ++j) {
        acc[j] += __shfl_xor(acc[j], 4, 64);
        acc[j] += __shfl_xor(acc[j], 8, 64);
        acc[j] += __shfl_xor(acc[j], 16, 64);
        acc[j] += __shfl_xor(acc[j], 32, 64);
    }
    sumw += __shfl_xor(sumw, 4, 64);
    sumw += __shfl_xor(sumw, 8, 64);
    sumw += __shfl_xor(sumw, 16, 64);
    sumw += __shfl_xor(sumw, 32, 64);
    if (slot == 0) {
        float inv = 1.f / (sumw + 1e-16f);
        float4 ba = ((const float4*)b2)[2 * chunk];
        float4 bb = ((const float4*)b2)[2 * chunk + 1];
        float o[8];
        o[0] = acc[0] * inv + ba.x; o[1] = acc[1] * inv + ba.y;
        o[2] = acc[2] * inv + ba.z; o[3] = acc[3] * inv + ba.w;
        o[4] = acc[4] * inv + bb.x; o[5] = acc[5] * inv + bb.y;
        o[6] = acc[6] * inv + bb.z; o[7] = acc[7] * inv + bb.w;
#pragma unroll
        for (int j = 0; j < 8; ++j) o[j] = o[j] > 0.f ? o[j] : expm1f(o[j]);
        float* dst = out2 + (size_t)n * C2 + 8 * chunk;
        *(float4*)dst = make_float4(o[0], o[1], o[2], o[3]);
        *(float4*)(dst + 4) = make_float4(o[4], o[5], o[6], o[7]);
    }
}

// ---- mean-pool per graph + MLP head ----
__global__ void k_pool(const float* __restrict__ out2, const int* __restrict__ batch,
                       int N, const float* __restrict__ Wh1, const float* __restrict__ bh1,
                       const float* __restrict__ Wh2, const float* __restrict__ bh2,
                       float* __restrict__ out) {
    int g = blockIdx.x;
    int t = threadIdx.x;
    __shared__ int sb[2];
    __shared__ float pooled[C2];
    __shared__ float red[256];
    if (t < 2) {
        int target = g + t;
        int lo = 0, hi = N;
        while (lo < hi) { int mid = (lo + hi) >> 1; if (batch[mid] < target) lo = mid + 1; else hi = mid; }
        sb[t] = lo;
    }
    __syncthreads();
    int lo = sb[0], hi = sb[1];
    int c = t & 31, grp = t >> 5;
    float part = 0.f;
    for (int n = lo + grp; n < hi; n += 8) part += out2[n * C2 + c];
    red[t] = part;
    __syncthreads();
    if (t < 128) red[t] += red[t + 128];
    __syncthreads();
    if (t < 64) red[t] += red[t + 64];
    __syncthreads();
    if (t < 32) {
        red[t] += red[t + 32];
        float cnt = (float)(hi - lo);
        pooled[t] = red[t] / fmaxf(cnt, 1.f);
    }
    __syncthreads();
    float hval = 0.f;
    if (t < HID) {
        float a = bh1[t];
#pragma unroll
        for (int cc = 0; cc < C2; ++cc) a += pooled[cc] * Wh1[cc * HID + t];
        hval = fmaxf(a, 0.f) * Wh2[t];
    }
    if (t < 64) {
        for (int o = 32; o > 0; o >>= 1) hval += __shfl_down(hval, o, 64);
        if (t == 0) out[g] = hval + bh2[0];
    }
}

extern "C" void kernel_launch(void* const* d_in, const int* in_sizes, int n_in,
                              void* d_out, int out_size, void* d_ws, size_t ws_size,
                              hipStream_t stream) {
    const float* x    = (const float*)d_in[0];
    const int*   ei   = (const int*)d_in[1];
    const int*   batch= (const int*)d_in[2];
    const float* W1   = (const float*)d_in[3];
    const float* aS1  = (const float*)d_in[4];
    const float* aD1  = (const float*)d_in[5];
    const float* b1   = (const float*)d_in[6];
    const float* W2   = (const float*)d_in[7];
    const float* aS2  = (const float*)d_in[8];
    const float* aD2  = (const float*)d_in[9];
    const float* b2   = (const float*)d_in[10];
    const float* Wh1  = (const float*)d_in[11];
    const float* bh1  = (const float*)d_in[12];
    const float* Wh2  = (const float*)d_in[13];
    const float* bh2  = (const float*)d_in[14];
    float* out = (float*)d_out;

    int N = in_sizes[2];
    int E = in_sizes[1] / 2;
    int M = E + N;
    int G = out_size;
    int nbk = (N + 255) >> 8;
    int nchunk = (M + CHUNK - 1) / CHUNK;
    int nlin = (N + 3) / 4;

    char* p = (char*)d_ws;
    auto alloc = [&](size_t bytes) -> void* {
        void* r = (void*)p;
        p += (bytes + 255) & ~(size_t)255;
        return r;
    };
    __half2* h1h   = (__half2*)alloc((size_t)N * 64 * 4);   // N x 128 fp16
    __half2* out1h = (__half2*)alloc((size_t)N * 64 * 4);
    __half2* h2h   = (__half2*)alloc((size_t)N * 16 * 4);   // N x 32 fp16
    float* as1     = (float*)alloc((size_t)N * NH1 * 4);
    float* ad1     = (float*)alloc((size_t)N * NH1 * 4);
    float* as2     = (float*)alloc((size_t)N * 4);
    float* ad2     = (float*)alloc((size_t)N * 4);
    float* out2    = (float*)alloc((size_t)N * C2 * 4);
    int*   offsets = (int*)alloc((size_t)(N + 1) * 4);
    int*   elist   = (int*)alloc((size_t)M * 4);
    int*   cursors = (int*)alloc(256 * 4);
    int*   buckets = (int*)alloc((size_t)nbk * CAP * 4);

    hipMemsetAsync(cursors, 0, 256 * 4, stream);
    k_front<<<nchunk + nlin, 256, 0, stream>>>(ei, E, N, nchunk, cursors, buckets,
                                               x, (const float2*)W1, (const float2*)aS1,
                                               (const float2*)aD1, h1h, as1, ad1);
    k_build<<<nbk, 256, 0, stream>>>(buckets, cursors, N, M, offsets, elist);
    k_agg1<<<(N + 3) / 4, 256, 0, stream>>>(offsets, elist, (const char*)as1, ad1,
                                            (const char*)h1h, b1, N, (float4*)out1h);
    k_lin2<<<(N + TN - 1) / TN, 256, 0, stream>>>(out1h, W2, aS2, aD2, N, h2h, as2, ad2);
    k_agg2<<<(N + 3) / 4, 256, 0, stream>>>(offsets, elist, (const char*)as2, ad2,
                                            (const char*)h2h, b2, N, out2);
    k_pool<<<G, 256, 0, stream>>>(out2, batch, N, Wh1, bh1, Wh2, bh2, out);
}

// Round 9
// 279.113 us; speedup vs baseline: 1.5204x; 1.0162x over previous
//
#include <hip/hip_runtime.h>
#include <hip/hip_fp16.h>
#include <math.h>

#define IN_CH 16
#define HC1 128   // H1*C1
#define NH1 4
#define C2 32
#define HID 64
#define NEG 0.2f
#define CAP 10240     // per-bucket capacity (mean ~8450, +20 sigma)
#define CHUNK 4096    // edges per bucket block

__device__ __forceinline__ float lrelu_exp_fast(float z) {
    float lr = fmaxf(z, NEG * z);   // leaky-relu via max (exact for neg_slope<1)
    return __expf(lr);
}

// v_fma_mix_f32: acc(f32) += f16half(hpack) * w(f32), full f32 fma precision.
__device__ __forceinline__ void fma_mix_lo(float& acc, int hpack, float w) {
    asm("v_fma_mix_f32 %0, %1, %2, %0 op_sel:[0,0,0] op_sel_hi:[1,0,0]"
        : "+v"(acc) : "v"(hpack), "v"(w));
}
__device__ __forceinline__ void fma_mix_hi(float& acc, int hpack, float w) {
    asm("v_fma_mix_f32 %0, %1, %2, %0 op_sel:[1,0,0] op_sel_hi:[1,0,0]"
        : "+v"(acc) : "v"(hpack), "v"(w));
}

// ---- Fused front: bucket-append (blocks [0,nchunk)) + GAT1 linear (rest) ----
__global__ void k_front(const int* __restrict__ ei, int E, int N, int nchunk,
                        int* __restrict__ cursors, int* __restrict__ buckets,
                        const float* __restrict__ x, const float2* __restrict__ W1v,
                        const float2* __restrict__ att_s2, const float2* __restrict__ att_d2,
                        __half2* __restrict__ h1h, float* __restrict__ as1, float* __restrict__ ad1) {
    int bid = blockIdx.x;
    if (bid < nchunk) {
        __shared__ int cnt[256];
        __shared__ int base[256];
        __shared__ int pos[256];
        int t = threadIdx.x;
        int c0 = bid * CHUNK;
        int M = E + N;
        cnt[t] = 0;
        pos[t] = 0;
        __syncthreads();
        int srcv[16], dstv[16];
#pragma unroll
        for (int k = 0; k < 16; ++k) {
            int i = c0 + k * 256 + t;
            int s = -1, d = -1;
            if (i < M) {
                if (i < E) { s = ei[i]; d = ei[E + i]; }
                else       { s = d = i - E; }
                atomicAdd(&cnt[d >> 8], 1);
            }
            srcv[k] = s; dstv[k] = d;
        }
        __syncthreads();
        if (cnt[t] > 0) base[t] = atomicAdd(&cursors[t], cnt[t]);
        __syncthreads();
#pragma unroll
        for (int k = 0; k < 16; ++k) {
            int d = dstv[k];
            if (d >= 0) {
                int b = d >> 8;
                int p = base[b] + atomicAdd(&pos[b], 1);
                buckets[b * CAP + p] = (srcv[k] << 8) | (d & 255);
            }
        }
    } else {
        int wave = threadIdx.x >> 6;
        int lane = threadIdx.x & 63;
        int n = (bid - nchunk) * 4 + wave;
        if (n >= N) return;
        float xv = x[n * IN_CH + (lane & 15)];
        float ax = 0.f, ay = 0.f;
#pragma unroll
        for (int k = 0; k < IN_CH; ++k) {
            float xk = __shfl(xv, k, 16);
            float2 w = W1v[k * 64 + lane];
            ax += xk * w.x;
            ay += xk * w.y;
        }
        h1h[(size_t)n * 64 + lane] = __floats2half2_rn(ax, ay);
        float2 s2 = att_s2[lane], d2 = att_d2[lane];
        float vs = ax * s2.x + ay * s2.y;
        float vd = ax * d2.x + ay * d2.y;
#pragma unroll
        for (int o = 1; o < 16; o <<= 1) {
            vs += __shfl_xor(vs, o, 64);
            vd += __shfl_xor(vd, o, 64);
        }
        if ((lane & 15) == 0) {
            as1[n * NH1 + (lane >> 4)] = vs;
            ad1[n * NH1 + (lane >> 4)] = vd;
        }
    }
}

// ---- CSR build: one block per bucket; inline scan of bucket counts ----
__global__ void k_build(const int* __restrict__ buckets, const int* __restrict__ cursors,
                        int N, int M,
                        int* __restrict__ offsets, int* __restrict__ elist) {
    __shared__ int sc[256];
    __shared__ int deg[256];
    __shared__ int cur[256];
    int b = blockIdx.x, t = threadIdx.x;
    int cv = cursors[t];
    sc[t] = cv;
    __syncthreads();
    for (int o = 1; o < 256; o <<= 1) {
        int a = (t >= o) ? sc[t - o] : 0;
        __syncthreads();
        sc[t] += a;
        __syncthreads();
    }
    int cnt = cursors[b];
    int gbase = sc[b] - cnt;
    int n0 = b << 8;
    const int* bk = buckets + b * CAP;
    deg[t] = 0;
    if (b == 0 && t == 0) offsets[N] = M;
    __syncthreads();
    for (int i = t; i < cnt; i += 256) atomicAdd(&deg[bk[i] & 255], 1);
    __syncthreads();
    int v = deg[t];
    sc[t] = v;
    __syncthreads();
    for (int o = 1; o < 256; o <<= 1) {
        int a = (t >= o) ? sc[t - o] : 0;
        __syncthreads();
        sc[t] += a;
        __syncthreads();
    }
    int excl = sc[t] - v;
    cur[t] = excl;
    if (n0 + t < N) offsets[n0 + t] = gbase + excl;
    __syncthreads();
    for (int i = t; i < cnt; i += 256) {
        int e = bk[i];
        int p = atomicAdd(&cur[e & 255], 1);
        elist[gbase + p] = e >> 8;
    }
}

// ---- GAT1 aggregation: one wave per dst; 4 edge-slots x 16 lanes x float4,
//      16 edges in flight; unsigned 32-bit offsets + v_fma_mix ----
__global__ void k_agg1(const int* __restrict__ offsets, const int* __restrict__ elist,
                       const char* __restrict__ as1b, const float* __restrict__ ad1,
                       const char* __restrict__ h1b, const float* __restrict__ b1,
                       int N, float4* __restrict__ out1q) {
    int wave = threadIdx.x >> 6;
    int lane = threadIdx.x & 63;
    int n = blockIdx.x * 4 + wave;
    if (n >= N) return;
    int slot = lane >> 4, chunk = lane & 15, head = chunk >> 2;
    int lo = offsets[n], hi = offsets[n + 1];
    float adh = ad1[n * NH1 + head];
    unsigned coff = (unsigned)(chunk << 4);   // byte offset within 256B h1 row
    unsigned hoff = (unsigned)(head << 2);    // byte offset within 16B as1 row
    float acc[8];
#pragma unroll
    for (int j = 0; j < 8; ++j) acc[j] = 0.f;
    float sumw = 0.f;
    for (int e0 = lo; e0 < hi; e0 += 16) {
        unsigned s[4]; bool ok[4]; float z[4]; float4 v[4]; float w[4];
#pragma unroll
        for (int u = 0; u < 4; ++u) {
            int ee = e0 + 4 * u + slot;
            ok[u] = ee < hi;
            s[u] = (unsigned)elist[ok[u] ? ee : lo];
        }
#pragma unroll
        for (int u = 0; u < 4; ++u) {
            z[u] = *(const float*)(as1b + (s[u] * 16u + hoff));
            v[u] = *(const float4*)(h1b + (s[u] * 256u + coff));
        }
#pragma unroll
        for (int u = 0; u < 4; ++u)
            w[u] = ok[u] ? lrelu_exp_fast(z[u] + adh) : 0.f;
#pragma unroll
        for (int u = 0; u < 4; ++u) {
            const int* hp = (const int*)&v[u];
            fma_mix_lo(acc[0], hp[0], w[u]); fma_mix_hi(acc[1], hp[0], w[u]);
            fma_mix_lo(acc[2], hp[1], w[u]); fma_mix_hi(acc[3], hp[1], w[u]);
            fma_mix_lo(acc[4], hp[2], w[u]); fma_mix_hi(acc[5], hp[2], w[u]);
            fma_mix_lo(acc[6], hp[3], w[u]); fma_mix_hi(acc[7], hp[3], w[u]);
            sumw += w[u];
        }
    }
#pragma unroll
    for (int j = 0; j < 8; ++j) {
        acc[j] += __shfl_xor(acc[j], 16, 64);
        acc[j] += __shfl_xor(acc[j], 32, 64);
    }
    sumw += __shfl_xor(sumw, 16, 64);
    sumw += __shfl_xor(sumw, 32, 64);
    if (slot == 0) {
        float inv = 1.f / (sumw + 1e-16f);
        float4 ba = ((const float4*)b1)[2 * chunk];
        float4 bb = ((const float4*)b1)[2 * chunk + 1];
        float o[8];
        o[0] = acc[0] * inv + ba.x; o[1] = acc[1] * inv + ba.y;
        o[2] = acc[2] * inv + ba.z; o[3] = acc[3] * inv + ba.w;
        o[4] = acc[4] * inv + bb.x; o[5] = acc[5] * inv + bb.y;
        o[6] = acc[6] * inv + bb.z; o[7] = acc[7] * inv + bb.w;
#pragma unroll
        for (int j = 0; j < 8; ++j) o[j] = o[j] > 0.f ? o[j] : expm1f(o[j]);
        float4 pk;
        __half2* ph = (__half2*)&pk;
        ph[0] = __floats2half2_rn(o[0], o[1]);
        ph[1] = __floats2half2_rn(o[2], o[3]);
        ph[2] = __floats2half2_rn(o[4], o[5]);
        ph[3] = __floats2half2_rn(o[6], o[7]);
        out1q[(size_t)n * 16 + chunk] = pk;
    }
}

// ---- GAT2 linear: LDS-tiled GEMM [N,128](fp16) x [128,32] + logits ----
#define TN 64
__global__ void k_lin2(const __half2* __restrict__ out1h, const float* __restrict__ W2,
                       const float* __restrict__ att_s, const float* __restrict__ att_d,
                       int N, __half2* __restrict__ h2h, float* __restrict__ as2, float* __restrict__ ad2) {
    __shared__ float sx[TN][HC1 + 1];
    __shared__ float sw[HC1][C2];
    int t = threadIdx.x;  // 256
    int base = blockIdx.x * TN;
    int lim = (N - base) * HC1;
    for (int i = t * 4; i < HC1 * C2; i += 1024) {
        float4 v = *(const float4*)(W2 + i);
        sw[i >> 5][i & 31] = v.x;
        sw[i >> 5][(i & 31) + 1] = v.y;
        sw[i >> 5][(i & 31) + 2] = v.z;
        sw[i >> 5][(i & 31) + 3] = v.w;
    }
    for (int i = t * 4; i < TN * HC1; i += 1024) {
        float2 a = make_float2(0.f, 0.f), b = make_float2(0.f, 0.f);
        if (i < lim) {
            size_t idx = ((size_t)base * HC1 + i) >> 1;
            a = __half22float2(out1h[idx]);
            b = __half22float2(out1h[idx + 1]);
        }
        int nn = i >> 7, kk = i & 127;
        sx[nn][kk] = a.x; sx[nn][kk + 1] = a.y; sx[nn][kk + 2] = b.x; sx[nn][kk + 3] = b.y;
    }
    __syncthreads();
    int nloc = t >> 2;
    int c0 = (t & 3) * 8;
    float acc[8];
#pragma unroll
    for (int j = 0; j < 8; ++j) acc[j] = 0.f;
#pragma unroll 4
    for (int k = 0; k < HC1; ++k) {
        float xv = sx[nloc][k];
        float4 wa = *(float4*)&sw[k][c0];
        float4 wb = *(float4*)&sw[k][c0 + 4];
        acc[0] += xv * wa.x; acc[1] += xv * wa.y; acc[2] += xv * wa.z; acc[3] += xv * wa.w;
        acc[4] += xv * wb.x; acc[5] += xv * wb.y; acc[6] += xv * wb.z; acc[7] += xv * wb.w;
    }
    int n = base + nloc;
    if (n < N) {
#pragma unroll
        for (int j = 0; j < 4; ++j)
            h2h[(size_t)n * 16 + (c0 >> 1) + j] = __floats2half2_rn(acc[2 * j], acc[2 * j + 1]);
        float ps = 0.f, pd = 0.f;
#pragma unroll
        for (int j = 0; j < 8; ++j) {
            ps += acc[j] * att_s[c0 + j];
            pd += acc[j] * att_d[c0 + j];
        }
        ps += __shfl_down(ps, 1, 64); ps += __shfl_down(ps, 2, 64);
        pd += __shfl_down(pd, 1, 64); pd += __shfl_down(pd, 2, 64);
        if ((t & 3) == 0) { as2[n] = ps; ad2[n] = pd; }
    }
}

// ---- GAT2 aggregation: one wave per dst; 16 edge-slots x 4 lanes x float4,
//      32 edges in flight; unsigned 32-bit offsets + v_fma_mix ----
__global__ void k_agg2(const int* __restrict__ offsets, const int* __restrict__ elist,
                       const char* __restrict__ as2b, const float* __restrict__ ad2,
                       const char* __restrict__ h2b, const float* __restrict__ b2,
                       int N, float* __restrict__ out2) {
    int wave = threadIdx.x >> 6;
    int lane = threadIdx.x & 63;
    int n = blockIdx.x * 4 + wave;
    if (n >= N) return;
    int slot = lane >> 2, chunk = lane & 3;
    int lo = offsets[n], hi = offsets[n + 1];
    float ad = ad2[n];
    unsigned coff = (unsigned)(chunk << 4);   // byte offset within 64B h2 row
    float acc[8];
#pragma unroll
    for (int j = 0; j < 8; ++j) acc[j] = 0.f;
    float sumw = 0.f;
    for (int e0 = lo; e0 < hi; e0 += 32) {
        unsigned s[2]; bool ok[2]; float z[2]; float4 v[2]; float w[2];
#pragma unroll
        for (int u = 0; u < 2; ++u) {
            int ee = e0 + 16 * u + slot;
            ok[u] = ee < hi;
            s[u] = (unsigned)elist[ok[u] ? ee : lo];
        }
#pragma unroll
        for (int u = 0; u < 2; ++u) {
            z[u] = *(const float*)(as2b + (s[u] * 4u));
            v[u] = *(const float4*)(h2b + (s[u] * 64u + coff));
        }
#pragma unroll
        for (int u = 0; u < 2; ++u)
            w[u] = ok[u] ? lrelu_exp_fast(z[u] + ad) : 0.f;
#pragma unroll
        for (int u = 0; u < 2; ++u) {
            const int* hp = (const int*)&v[u];
            fma_mix_lo(acc[0], hp[0], w[u]); fma_mix_hi(acc[1], hp[0], w[u]);
            fma_mix_lo(acc[2], hp[1], w[u]); fma_mix_hi(acc[3], hp[1], w[u]);
            fma_mix_lo(acc[4], hp[2], w[u]); fma_mix_hi(acc[5], hp[2], w[u]);
            fma_mix_lo(acc[6], hp[3], w[u]); fma_mix_hi(acc[7], hp[3], w[u]);
            sumw += w[u];
        }
    }
#pragma unroll
    for (int j = 0; j < 8; ++j) {
        acc[j] += __shfl_xor(acc[j], 4, 64);
        acc[j] += __shfl_xor(acc[j], 8, 64);
        acc[j] += __shfl_xor(acc[j], 16, 64);
        acc[j] += __shfl_xor(acc[j], 32, 64);
    }
    sumw += __shfl_xor(sumw, 4, 64);
    sumw += __shfl_xor(sumw, 8, 64);
    sumw += __shfl_xor(sumw, 16, 64);
    sumw += __shfl_xor(sumw, 32, 64);
    if (slot == 0) {
        float inv = 1.f / (sumw + 1e-16f);
        float4 ba = ((const float4*)b2)[2 * chunk];
        float4 bb = ((const float4*)b2)[2 * chunk + 1];
        float o[8];
        o[0] = acc[0] * inv + ba.x; o[1] = acc[1] * inv + ba.y;
        o[2] = acc[2] * inv + ba.z; o[3] = acc[3] * inv + ba.w;
        o[4] = acc[4] * inv + bb.x; o[5] = acc[5] * inv + bb.y;
        o[6] = acc[6] * inv + bb.z; o[7] = acc[7] * inv + bb.w;
#pragma unroll
        for (int j = 0; j < 8; ++j) o[j] = o[j] > 0.f ? o[j] : expm1f(o[j]);
        float* dst = out2 + (size_t)n * C2 + 8 * chunk;
        *(float4*)dst = make_float4(o[0], o[1], o[2], o[3]);
        *(float4*)(dst + 4) = make_float4(o[4], o[5], o[6], o[7]);
    }
}

// ---- mean-pool per graph + MLP head ----
__global__ void k_pool(const float* __restrict__ out2, const int* __restrict__ batch,
                       int N, const float* __restrict__ Wh1, const float* __restrict__ bh1,
                       const float* __restrict__ Wh2, const float* __restrict__ bh2,
                       float* __restrict__ out) {
    int g = blockIdx.x;
    int t = threadIdx.x;
    __shared__ int sb[2];
    __shared__ float pooled[C2];
    __shared__ float red[256];
    if (t < 2) {
        int target = g + t;
        int lo = 0, hi = N;
        while (lo < hi) { int mid = (lo + hi) >> 1; if (batch[mid] < target) lo = mid + 1; else hi = mid; }
        sb[t] = lo;
    }
    __syncthreads();
    int lo = sb[0], hi = sb[1];
    int c = t & 31, grp = t >> 5;
    float part = 0.f;
    for (int n = lo + grp; n < hi; n += 8) part += out2[n * C2 + c];
    red[t] = part;
    __syncthreads();
    if (t < 128) red[t] += red[t + 128];
    __syncthreads();
    if (t < 64) red[t] += red[t + 64];
    __syncthreads();
    if (t < 32) {
        red[t] += red[t + 32];
        float cnt = (float)(hi - lo);
        pooled[t] = red[t] / fmaxf(cnt, 1.f);
    }
    __syncthreads();
    float hval = 0.f;
    if (t < HID) {
        float a = bh1[t];
#pragma unroll
        for (int cc = 0; cc < C2; ++cc) a += pooled[cc] * Wh1[cc * HID + t];
        hval = fmaxf(a, 0.f) * Wh2[t];
    }
    if (t < 64) {
        for (int o = 32; o > 0; o >>= 1) hval += __shfl_down(hval, o, 64);
        if (t == 0) out[g] = hval + bh2[0];
    }
}

extern "C" void kernel_launch(void* const* d_in, const int* in_sizes, int n_in,
                              void* d_out, int out_size, void* d_ws, size_t ws_size,
                              hipStream_t stream) {
    const float* x    = (const float*)d_in[0];
    const int*   ei   = (const int*)d_in[1];
    const int*   batch= (const int*)d_in[2];
    const float* W1   = (const float*)d_in[3];
    const float* aS1  = (const float*)d_in[4];
    const float* aD1  = (const float*)d_in[5];
    const float* b1   = (const float*)d_in[6];
    const float* W2   = (const float*)d_in[7];
    const float* aS2  = (const float*)d_in[8];
    const float* aD2  = (const float*)d_in[9];
    const float* b2   = (const float*)d_in[10];
    const float* Wh1  = (const float*)d_in[11];
    const float* bh1  = (const float*)d_in[12];
    const float* Wh2  = (const float*)d_in[13];
    const float* bh2  = (const float*)d_in[14];
    float* out = (float*)d_out;

    int N = in_sizes[2];
    int E = in_sizes[1] / 2;
    int M = E + N;
    int G = out_size;
    int nbk = (N + 255) >> 8;
    int nchunk = (M + CHUNK - 1) / CHUNK;
    int nlin = (N + 3) / 4;

    char* p = (char*)d_ws;
    auto alloc = [&](size_t bytes) -> void* {
        void* r = (void*)p;
        p += (bytes + 255) & ~(size_t)255;
        return r;
    };
    __half2* h1h   = (__half2*)alloc((size_t)N * 64 * 4);   // N x 128 fp16
    __half2* out1h = (__half2*)alloc((size_t)N * 64 * 4);
    __half2* h2h   = (__half2*)alloc((size_t)N * 16 * 4);   // N x 32 fp16
    float* as1     = (float*)alloc((size_t)N * NH1 * 4);
    float* ad1     = (float*)alloc((size_t)N * NH1 * 4);
    float* as2     = (float*)alloc((size_t)N * 4);
    float* ad2     = (float*)alloc((size_t)N * 4);
    float* out2    = (float*)alloc((size_t)N * C2 * 4);
    int*   offsets = (int*)alloc((size_t)(N + 1) * 4);
    int*   elist   = (int*)alloc((size_t)M * 4);
    int*   cursors = (int*)alloc(256 * 4);
    int*   buckets = (int*)alloc((size_t)nbk * CAP * 4);

    hipMemsetAsync(cursors, 0, 256 * 4, stream);
    k_front<<<nchunk + nlin, 256, 0, stream>>>(ei, E, N, nchunk, cursors, buckets,
                                               x, (const float2*)W1, (const float2*)aS1,
                                               (const float2*)aD1, h1h, as1, ad1);
    k_build<<<nbk, 256, 0, stream>>>(buckets, cursors, N, M, offsets, elist);
    k_agg1<<<(N + 3) / 4, 256, 0, stream>>>(offsets, elist, (const char*)as1, ad1,
                                            (const char*)h1h, b1, N, (float4*)out1h);
    k_lin2<<<(N + TN - 1) / TN, 256, 0, stream>>>(out1h, W2, aS2, aD2, N, h2h, as2, ad2);
    k_agg2<<<(N + 3) / 4, 256, 0, stream>>>(offsets, elist, (const char*)as2, ad2,
                                            (const char*)h2h, b2, N, out2);
    k_pool<<<G, 256, 0, stream>>>(out2, batch, N, Wh1, bh1, Wh2, bh2, out);
}